// Round 7
// baseline (393.371 us; speedup 1.0000x reference)
//
#include <hip/hip_runtime.h>

#define N_NODES 20000
#define N_EDGES 100000
#define DIM 32
#define R2 100
#define NLAYERS 4
#define BATCH 4
#define NEG 32
#define NREP 3
#define BS (NREP * BATCH)          // 12
#define RELDIM (R2 * DIM)          // 3200

#define NPB 4                      // nodes per block
#define TPN 96                     // threads per node = 12 r * 8 lanes
#define LBLK (NPB * TPN)           // 384
#define GRID_LAYER (N_NODES / NPB) // 5000

// ---------------- workspace layout (floats then ints) ----------------
// x: [N][BS][DIM] node-major; pb: [N][BS]; rel: [L][R2][BS][DIM]
#define XO_A 0
#define XO_B (XO_A + (size_t)N_NODES * BS * DIM)
#define PBO_A (XO_B + (size_t)N_NODES * BS * DIM)
#define PBO_B (PBO_A + (size_t)N_NODES * BS)
#define RELO (PBO_B + (size_t)N_NODES * BS)
#define QO (RELO + (size_t)NLAYERS * R2 * BS * DIM)
#define FLOAT_TOTAL (QO + (size_t)BS * DIM)

#define IO_H0 0
#define IO_TIDX (IO_H0 + BS)
#define IO_COUNTS (IO_TIDX + BS * NEG)
#define IO_OFF (IO_COUNTS + N_NODES)
#define IO_BCUR (IO_OFF + N_NODES + 1)
#define IO_CURSOR (IO_BCUR + 256)
#define IO_ORDER (IO_CURSOR + N_NODES)
#define IO_PAD (IO_ORDER + N_NODES)
#define IO_ES (((IO_PAD + 1) / 2) * 2)        // int2-aligned
#define INT_TOTAL (IO_ES + 2 * N_EDGES)

// ---------------------------------------------------------------------
__global__ void k_init(const int* __restrict__ batch,
                       const float* __restrict__ start_query,
                       float* __restrict__ q, int* __restrict__ h0,
                       int* __restrict__ t_idx) {
    int r = threadIdx.x;
    if (r >= BS) return;
    int b = r % BATCH, rep = r / BATCH;
    int h00 = batch[(b * NEG + 0) * 2 + 0];
    bool is_t_neg = true;
    for (int j = 0; j < NEG; j++)
        if (batch[(b * NEG + j) * 2 + 0] != h00) { is_t_neg = false; break; }
    int hsel = is_t_neg ? 0 : 1;
    int h0v = batch[(b * NEG + 0) * 2 + hsel];
    h0[r] = h0v;
    for (int j = 0; j < NEG; j++)
        t_idx[r * NEG + j] = batch[(b * NEG + j) * 2 + (1 - hsel)];
    for (int d = 0; d < DIM; d++) q[r * DIM + d] = start_query[rep * DIM + d];
}

__global__ void k_count(const int* __restrict__ dst, int* __restrict__ counts) {
    int e = blockIdx.x * blockDim.x + threadIdx.x;
    if (e < N_EDGES) atomicAdd(&counts[dst[e]], 1);
}

// CSR offsets + degree histogram -> bucket cursors (for degree-sorted order)
__global__ void k_scan(const int* __restrict__ counts, int* __restrict__ off,
                       int* __restrict__ cursor, int* __restrict__ bcursor) {
    __shared__ int sd[1024];
    __shared__ int hist[256];
    int t = threadIdx.x;
    const int CH = (N_NODES + 1023) / 1024;  // 20
    int base = t * CH;
    for (int i = t; i < 256; i += 1024) hist[i] = 0;
    int sum = 0;
    for (int i = 0; i < CH; i++) {
        int idx = base + i;
        if (idx < N_NODES) sum += counts[idx];
    }
    sd[t] = sum;
    __syncthreads();
    for (int o = 1; o < 1024; o <<= 1) {
        int v = (t >= o) ? sd[t - o] : 0;
        __syncthreads();
        sd[t] += v;
        __syncthreads();
    }
    int excl = sd[t] - sum;
    int run = excl;
    for (int i = 0; i < CH; i++) {
        int idx = base + i;
        if (idx < N_NODES) {
            int c = counts[idx];
            off[idx] = run;
            cursor[idx] = run;
            run += c;
            atomicAdd(&hist[c < 255 ? c : 255], 1);
        }
    }
    if (t == 1023) off[N_NODES] = sd[1023];
    __syncthreads();
    if (t == 0) {
        int acc = 0;
        for (int b = 0; b < 256; b++) { bcursor[b] = acc; acc += hist[b]; }
    }
}

// place edges in CSR order; pack {src | etype<<20, e}
__global__ void k_place(const int* __restrict__ src, const int* __restrict__ dst,
                        const int* __restrict__ etype, int* __restrict__ cursor,
                        int2* __restrict__ es) {
    int e = blockIdx.x * blockDim.x + threadIdx.x;
    if (e < N_EDGES) {
        int p = atomicAdd(&cursor[dst[e]], 1);
        es[p] = make_int2(src[e] | (etype[e] << 20), e);
    }
}

// degree-sorted node order (counting sort by degree)
__global__ void k_order(const int* __restrict__ counts, int* __restrict__ bcursor,
                        int* __restrict__ node_order) {
    int n = blockIdx.x * blockDim.x + threadIdx.x;
    if (n < N_NODES) {
        int deg = counts[n]; if (deg > 255) deg = 255;
        int pos = atomicAdd(&bcursor[deg], 1);
        node_order[pos] = n;
    }
}

// rel[l][et][r][d]
__global__ void k_rel_all(const float* __restrict__ q, const float* __restrict__ W_rel,
                          const float* __restrict__ b_rel, float* __restrict__ rel) {
    int idx = blockIdx.x * blockDim.x + threadIdx.x;
    if (idx >= NLAYERS * R2 * BS * DIM) return;
    int d = idx & 31;
    int r = (idx >> 5) % BS;
    int et = (idx / (BS * DIM)) % R2;
    int l = idx / (R2 * BS * DIM);
    int c = et * DIM + d;
    const float* W = W_rel + (size_t)l * DIM * RELDIM;
    float acc = b_rel[l * RELDIM + c];
    #pragma unroll
    for (int k = 0; k < DIM; k++) acc += q[r * DIM + k] * W[(size_t)k * RELDIM + c];
    rel[idx] = acc;
}

// Fused layer. thread = gi*96 + r*8 + l; nodes via degree-sorted node_order.
// L0: output is relu(b_lin) broadcast except for blocks touching h0 / h0-out-edges.
template <bool L0>
__launch_bounds__(LBLK)
__global__ void k_layer(const float* __restrict__ x_old, const float* __restrict__ pb_old,
                        const float* __restrict__ rel_l, const float* __restrict__ edge_attr,
                        const int2* __restrict__ es, const int* __restrict__ off,
                        const int* __restrict__ node_order,
                        const int* __restrict__ h0, const float* __restrict__ q,
                        const float* __restrict__ W_lin_l, const float* __restrict__ b_lin_l,
                        float* __restrict__ x_new, float* __restrict__ pb_new) {
    __shared__ float sW[64 * DIM];           // 8 KB
    __shared__ float sB[DIM];
    __shared__ float sIn[NPB * BS * 68];     // 13056 B
    __shared__ int sFlag;

    const int gi = threadIdx.x / TPN;        // node in block 0..3
    const int t = threadIdx.x % TPN;
    const int r = t >> 3;                    // 0..11
    const int l = t & 7;                     // 0..7
    const int n = node_order[blockIdx.x * NPB + gi];

    const int h0r = h0[r];
    const float4 q4 = *(const float4*)(q + r * DIM + l * 4);
    const int s0 = off[n], s1 = off[n + 1];

    if (L0) {
        // cheap index-only scan: is this (n,r) touched by the boundary?
        if (threadIdx.x == 0) sFlag = 0;
        bool spec = (n == h0r);
        for (int k = s0; k < s1; k++) {
            int2 p2 = es[k];
            if ((p2.x & 0xFFFFF) == h0r) spec = true;
        }
        __syncthreads();
        if (spec) sFlag = 1;
        __syncthreads();
        if (!sFlag) {
            // whole block untouched: out = relu(b_lin), pb = 0
            float4 b4 = *(const float4*)(b_lin_l + l * 4);
            b4.x = fmaxf(b4.x, 0.f); b4.y = fmaxf(b4.y, 0.f);
            b4.z = fmaxf(b4.z, 0.f); b4.w = fmaxf(b4.w, 0.f);
            *(float4*)(x_new + ((size_t)n * BS + r) * DIM + l * 4) = b4;
            if (l == 0) pb_new[n * BS + r] = 0.f;
            return;
        }
    }

    for (int i = threadIdx.x; i < 64 * DIM; i += LBLK) sW[i] = W_lin_l[i];
    if (threadIdx.x < DIM) sB[threadIdx.x] = b_lin_l[threadIdx.x];

    float4 xr4, ag4 = make_float4(0.f, 0.f, 0.f, 0.f);
    float pbm;
    if (L0) {
        xr4 = (n == h0r) ? q4 : make_float4(0.f, 0.f, 0.f, 0.f);
        pbm = (n == h0r) ? 1.f : 0.f;
    } else {
        xr4 = *(const float4*)(x_old + ((size_t)n * BS + r) * DIM + l * 4);
        pbm = pb_old[n * BS + r];
    }

    for (int k = s0; k < s1; k++) {
        int2 p2 = es[k];
        int s = p2.x & 0xFFFFF;
        int et = ((unsigned)p2.x) >> 20;
        int e = p2.y;
        if (L0) {
            if (s == h0r) {
                float4 rl = *(const float4*)(rel_l + ((size_t)et * BS + r) * DIM + l * 4);
                float4 ea = *(const float4*)(edge_attr + (size_t)e * DIM + l * 4);
                ag4.x += q4.x * (rl.x + ea.x);
                ag4.y += q4.y * (rl.y + ea.y);
                ag4.z += q4.z * (rl.z + ea.z);
                ag4.w += q4.w * (rl.w + ea.w);
                pbm = 1.f;
            }
        } else {
            float4 xs = *(const float4*)(x_old + ((size_t)s * BS + r) * DIM + l * 4);
            float4 rl = *(const float4*)(rel_l + ((size_t)et * BS + r) * DIM + l * 4);
            float4 ea = *(const float4*)(edge_attr + (size_t)e * DIM + l * 4);
            ag4.x += xs.x * (rl.x + ea.x);
            ag4.y += xs.y * (rl.y + ea.y);
            ag4.z += xs.z * (rl.z + ea.z);
            ag4.w += xs.w * (rl.w + ea.w);
            pbm = fmaxf(pbm, pb_old[s * BS + r]);
        }
    }
    if (n == h0r) {  // agg += boundary
        ag4.x += q4.x; ag4.y += q4.y; ag4.z += q4.z; ag4.w += q4.w;
    }

    float* srow = sIn + (gi * BS + r) * 68;
    *(float4*)(srow + l * 4) = xr4;          // concat [x | agg]
    *(float4*)(srow + 32 + l * 4) = ag4;
    __syncthreads();                          // covers sW/sB/sIn (block-uniform here)

    float4 acc = *(const float4*)(sB + l * 4);
    #pragma unroll
    for (int k4 = 0; k4 < 16; k4++) {
        float4 v = *(const float4*)(srow + k4 * 4);
        const float* wb = sW + (k4 * 4) * DIM + l * 4;
        float4 w0 = *(const float4*)(wb);
        float4 w1 = *(const float4*)(wb + DIM);
        float4 w2 = *(const float4*)(wb + 2 * DIM);
        float4 w3 = *(const float4*)(wb + 3 * DIM);
        acc.x += v.x * w0.x + v.y * w1.x + v.z * w2.x + v.w * w3.x;
        acc.y += v.x * w0.y + v.y * w1.y + v.z * w2.y + v.w * w3.y;
        acc.z += v.x * w0.z + v.y * w1.z + v.z * w2.z + v.w * w3.z;
        acc.w += v.x * w0.w + v.y * w1.w + v.z * w2.w + v.w * w3.w;
    }
    acc.x = fmaxf(acc.x, 0.f);
    acc.y = fmaxf(acc.y, 0.f);
    acc.z = fmaxf(acc.z, 0.f);
    acc.w = fmaxf(acc.w, 0.f);
    *(float4*)(x_new + ((size_t)n * BS + r) * DIM + l * 4) = acc;
    if (l == 0) pb_new[n * BS + r] = pbm;
}

// Data-parallel epilogue: 1 block x 1024 threads, LDS-staged.
__launch_bounds__(1024)
__global__ void k_final(const float* __restrict__ x, const float* __restrict__ pb,
                        const int* __restrict__ t_idx,
                        const float* __restrict__ W1, const float* __restrict__ b1,
                        const float* __restrict__ W2, const float* __restrict__ b2,
                        float* __restrict__ out) {
    __shared__ float sW1[DIM * DIM];
    __shared__ float sW2[DIM * DIM];
    __shared__ float sfeat[BATCH * NEG * DIM];
    __shared__ float shid[BATCH * NEG * DIM];
    const int t = threadIdx.x;
    const int NPAIR = BATCH * NEG;  // 128

    for (int i = t; i < DIM * DIM; i += 1024) { sW1[i] = W1[i]; sW2[i] = W2[i]; }

    for (int i = t; i < NPAIR * DIM; i += 1024) {
        int pair = i >> 5;
        int d = i & 31;
        int b = pair >> 5;
        int tt = t_idx[pair];
        float s = 0.f;
        #pragma unroll
        for (int rep = 0; rep < NREP; rep++)
            s += x[((size_t)tt * BS + rep * BATCH + b) * DIM + d];
        sfeat[i] = s * (1.f / 3.f);
    }
    __syncthreads();

    for (int i = t; i < NPAIR * DIM; i += 1024) {
        int pair = i >> 5;
        int jj = i & 31;
        float a = b1[jj];
        #pragma unroll
        for (int k = 0; k < DIM; k++)
            a += sfeat[pair * DIM + k] * sW1[k * DIM + jj];
        shid[i] = fmaxf(a, 0.f);
    }
    __syncthreads();

    for (int i = t; i < NPAIR * DIM; i += 1024) {
        int pair = i >> 5;
        int jj = i & 31;
        float a = b2[jj];
        #pragma unroll
        for (int k = 0; k < DIM; k++)
            a += shid[pair * DIM + k] * sW2[k * DIM + jj];
        out[i] = a;
    }

    if (t < NPAIR) {
        int b = t >> 5;
        int tt = t_idx[t];
        float pm = 0.f;
        #pragma unroll
        for (int rep = 0; rep < NREP; rep++)
            pm = fmaxf(pm, pb[(size_t)tt * BS + rep * BATCH + b]);
        out[NPAIR * DIM + t] = pm;
    }
}

// ---------------------------------------------------------------------
extern "C" void kernel_launch(void* const* d_in, const int* in_sizes, int n_in,
                              void* d_out, int out_size, void* d_ws, size_t ws_size,
                              hipStream_t stream) {
    const int* batch = (const int*)d_in[0];
    const int* edge_index = (const int*)d_in[1];
    const int* edge_type = (const int*)d_in[2];
    const float* edge_attr = (const float*)d_in[3];
    const float* start_query = (const float*)d_in[5];
    const float* W_rel = (const float*)d_in[6];
    const float* b_rel = (const float*)d_in[7];
    const float* W_lin = (const float*)d_in[8];
    const float* b_lin = (const float*)d_in[9];
    const float* W_mlp1 = (const float*)d_in[10];
    const float* b_mlp1 = (const float*)d_in[11];
    const float* W_mlp2 = (const float*)d_in[12];
    const float* b_mlp2 = (const float*)d_in[13];

    float* wf = (float*)d_ws;
    int* wi = (int*)(wf + FLOAT_TOTAL);
    size_t need = FLOAT_TOTAL * sizeof(float) + INT_TOTAL * sizeof(int);
    if (ws_size < need) return;

    float* x_a = wf + XO_A;
    float* x_b = wf + XO_B;
    float* pb_a = wf + PBO_A;
    float* pb_b = wf + PBO_B;
    float* rel = wf + RELO;
    float* q = wf + QO;
    int* h0 = wi + IO_H0;
    int* t_idx = wi + IO_TIDX;
    int* counts = wi + IO_COUNTS;
    int* off = wi + IO_OFF;
    int* bcursor = wi + IO_BCUR;
    int* cursor = wi + IO_CURSOR;
    int* node_order = wi + IO_ORDER;
    int2* es = (int2*)(wi + IO_ES);

    const int* src = edge_index;
    const int* dst = edge_index + N_EDGES;

    hipMemsetAsync(counts, 0, (size_t)N_NODES * sizeof(int), stream);

    k_init<<<1, 64, 0, stream>>>(batch, start_query, q, h0, t_idx);

    int eb = (N_EDGES + 255) / 256;
    int nb = (N_NODES + 255) / 256;
    k_count<<<eb, 256, 0, stream>>>(dst, counts);
    k_scan<<<1, 1024, 0, stream>>>(counts, off, cursor, bcursor);
    k_place<<<eb, 256, 0, stream>>>(src, dst, edge_type, cursor, es);
    k_order<<<nb, 256, 0, stream>>>(counts, bcursor, node_order);

    int relb = (NLAYERS * R2 * BS * DIM + 255) / 256;  // 600
    k_rel_all<<<relb, 256, 0, stream>>>(q, W_rel, b_rel, rel);

    // layer 0 (boundary input, fill+fix fast path) -> x_a, pb_a
    k_layer<true><<<GRID_LAYER, LBLK, 0, stream>>>(
        x_a, pb_a, rel, edge_attr, es, off, node_order, h0, q,
        W_lin, b_lin, x_a, pb_a);

    float* x_cur = x_a;
    float* x_nxt = x_b;
    float* pb_cur = pb_a;
    float* pb_nxt = pb_b;
    for (int l = 1; l < NLAYERS; l++) {
        k_layer<false><<<GRID_LAYER, LBLK, 0, stream>>>(
            x_cur, pb_cur, rel + (size_t)l * R2 * BS * DIM, edge_attr, es, off,
            node_order, h0, q,
            W_lin + (size_t)l * 64 * DIM, b_lin + (size_t)l * DIM,
            x_nxt, pb_nxt);
        float* tx = x_cur; x_cur = x_nxt; x_nxt = tx;
        float* tp = pb_cur; pb_cur = pb_nxt; pb_nxt = tp;
    }

    k_final<<<1, 1024, 0, stream>>>(x_cur, pb_cur, t_idx, W_mlp1, b_mlp1, W_mlp2, b_mlp2,
                                    (float*)d_out);
}

// Round 10
// 345.382 us; speedup vs baseline: 1.1389x; 1.1389x over previous
//
#include <hip/hip_runtime.h>

#define N_NODES 20000
#define N_EDGES 100000
#define DIM 32
#define R2 100
#define NLAYERS 4
#define BATCH 4
#define NEG 32
#define NREP 3
#define BS (NREP * BATCH)          // 12
#define RELDIM (R2 * DIM)          // 3200

#define NPB 4                      // nodes per block
#define TPN 96                     // threads per node = 12 r * 8 lanes
#define LBLK (NPB * TPN)           // 384
#define GRID_LAYER (N_NODES / NPB) // 5000

// merged prep kernel block ranges
#define EB ((N_EDGES + 255) / 256)            // 391  place
#define NB ((N_NODES + 255) / 256)            // 79   order
#define RELB ((NLAYERS * R2 * BS * DIM) / 256) // 600 rel
#define PREP_GRID (EB + NB + RELB)

// ---------------- workspace layout (floats then ints) ----------------
// x: [N][BS][DIM] node-major; pb: [N][BS]; rel: [L][R2][BS][DIM]
#define XO_A 0
#define XO_B (XO_A + (size_t)N_NODES * BS * DIM)
#define PBO_A (XO_B + (size_t)N_NODES * BS * DIM)
#define PBO_B (PBO_A + (size_t)N_NODES * BS)
#define RELO (PBO_B + (size_t)N_NODES * BS)
#define QO (RELO + (size_t)NLAYERS * R2 * BS * DIM)
#define FLOAT_TOTAL (QO + (size_t)BS * DIM)

#define IO_H0 0
#define IO_TIDX (IO_H0 + BS)
#define IO_COUNTS (IO_TIDX + BS * NEG)
#define IO_OFF (IO_COUNTS + N_NODES)
#define IO_BCUR (IO_OFF + N_NODES + 1)         // 256 buckets * 32-int stride
#define IO_CURSOR (IO_BCUR + 256 * 32)
#define IO_ORDER (IO_CURSOR + N_NODES)
#define IO_PAD (IO_ORDER + N_NODES)
#define IO_ES (((IO_PAD + 1) / 2) * 2)         // int2-aligned
#define INT_TOTAL (IO_ES + 2 * N_EDGES)

// ---------------------------------------------------------------------
__global__ void k_count(const int* __restrict__ dst, int* __restrict__ counts) {
    int e = blockIdx.x * blockDim.x + threadIdx.x;
    if (e < N_EDGES) atomicAdd(&counts[dst[e]], 1);
}

// CSR offsets + degree histogram -> LPT bucket bases; also folds k_init.
__global__ void k_scan(const int* __restrict__ counts, int* __restrict__ off,
                       int* __restrict__ cursor, int* __restrict__ bcursor,
                       const int* __restrict__ batch,
                       const float* __restrict__ start_query,
                       float* __restrict__ q, int* __restrict__ h0,
                       int* __restrict__ t_idx) {
    __shared__ int sd[1024];
    __shared__ int hist[256];
    int t = threadIdx.x;

    // ---- folded init (threads 0..11) ----
    if (t < BS) {
        int r = t;
        int b = r % BATCH, rep = r / BATCH;
        int h00 = batch[(b * NEG + 0) * 2 + 0];
        bool is_t_neg = true;
        for (int j = 0; j < NEG; j++)
            if (batch[(b * NEG + j) * 2 + 0] != h00) { is_t_neg = false; break; }
        int hsel = is_t_neg ? 0 : 1;
        int h0v = batch[(b * NEG + 0) * 2 + hsel];
        h0[r] = h0v;
        for (int j = 0; j < NEG; j++)
            t_idx[r * NEG + j] = batch[(b * NEG + j) * 2 + (1 - hsel)];
        for (int d = 0; d < DIM; d++) q[r * DIM + d] = start_query[rep * DIM + d];
    }

    const int CH = (N_NODES + 1023) / 1024;  // 20
    int base = t * CH;
    for (int i = t; i < 256; i += 1024) hist[i] = 0;
    int sum = 0;
    for (int i = 0; i < CH; i++) {
        int idx = base + i;
        if (idx < N_NODES) sum += counts[idx];
    }
    sd[t] = sum;
    __syncthreads();
    for (int o = 1; o < 1024; o <<= 1) {
        int v = (t >= o) ? sd[t - o] : 0;
        __syncthreads();
        sd[t] += v;
        __syncthreads();
    }
    int excl = sd[t] - sum;
    int run = excl;
    for (int i = 0; i < CH; i++) {
        int idx = base + i;
        if (idx < N_NODES) {
            int c = counts[idx];
            off[idx] = run;
            cursor[idx] = run;
            run += c;
            atomicAdd(&hist[c < 255 ? c : 255], 1);
        }
    }
    if (t == 1023) off[N_NODES] = sd[1023];
    __syncthreads();
    if (t == 0) {
        // LPT: descending degree -> highest-degree nodes first in node_order
        int acc = 0;
        for (int b = 255; b >= 0; b--) { bcursor[b * 32] = acc; acc += hist[b]; }
    }
}

// merged: edge placement | degree-bucket ordering | rel projection
__global__ void k_prep(const int* __restrict__ src, const int* __restrict__ dst,
                       const int* __restrict__ etype, int* __restrict__ cursor,
                       int2* __restrict__ es,
                       const int* __restrict__ counts, int* __restrict__ bcursor,
                       int* __restrict__ node_order,
                       const float* __restrict__ q, const float* __restrict__ W_rel,
                       const float* __restrict__ b_rel, float* __restrict__ rel) {
    int bid = blockIdx.x;
    if (bid < EB) {
        int e = bid * 256 + threadIdx.x;
        if (e < N_EDGES) {
            int p = atomicAdd(&cursor[dst[e]], 1);
            es[p] = make_int2(src[e] | (etype[e] << 20), e);
        }
    } else if (bid < EB + NB) {
        int n = (bid - EB) * 256 + threadIdx.x;
        if (n < N_NODES) {
            int deg = counts[n]; if (deg > 255) deg = 255;
            int pos = atomicAdd(&bcursor[deg * 32], 1);   // 128B-strided buckets
            node_order[pos] = n;
        }
    } else {
        int idx = (bid - EB - NB) * 256 + threadIdx.x;   // < NLAYERS*R2*BS*DIM
        int d = idx & 31;
        int r = (idx >> 5) % BS;
        int et = (idx / (BS * DIM)) % R2;
        int l = idx / (R2 * BS * DIM);
        int c = et * DIM + d;
        const float* W = W_rel + (size_t)l * DIM * RELDIM;
        float acc = b_rel[l * RELDIM + c];
        #pragma unroll
        for (int k = 0; k < DIM; k++) acc += q[r * DIM + k] * W[(size_t)k * RELDIM + c];
        rel[idx] = acc;
    }
}

// Fused layer. thread = gi*96 + r*8 + l; nodes via LPT-ordered node_order.
template <bool L0>
__launch_bounds__(LBLK)
__global__ void k_layer(const float* __restrict__ x_old, const float* __restrict__ pb_old,
                        const float* __restrict__ rel_l, const float* __restrict__ edge_attr,
                        const int2* __restrict__ es, const int* __restrict__ off,
                        const int* __restrict__ node_order,
                        const int* __restrict__ h0, const float* __restrict__ q,
                        const float* __restrict__ W_lin_l, const float* __restrict__ b_lin_l,
                        float* __restrict__ x_new, float* __restrict__ pb_new) {
    __shared__ float sW[64 * DIM];           // 8 KB
    __shared__ float sB[DIM];
    __shared__ float sIn[NPB * BS * 68];     // 13056 B
    __shared__ int sFlag;

    const int gi = threadIdx.x / TPN;        // node in block 0..3
    const int t = threadIdx.x % TPN;
    const int r = t >> 3;                    // 0..11
    const int l = t & 7;                     // 0..7
    const int n = node_order[blockIdx.x * NPB + gi];

    const int h0r = h0[r];
    const float4 q4 = *(const float4*)(q + r * DIM + l * 4);
    const int s0 = off[n], s1 = off[n + 1];

    if (L0) {
        if (threadIdx.x == 0) sFlag = 0;
        bool spec = (n == h0r);
        for (int k = s0; k < s1; k++) {
            int2 p2 = es[k];
            if ((p2.x & 0xFFFFF) == h0r) spec = true;
        }
        __syncthreads();
        if (spec) sFlag = 1;
        __syncthreads();
        if (!sFlag) {
            float4 b4 = *(const float4*)(b_lin_l + l * 4);
            b4.x = fmaxf(b4.x, 0.f); b4.y = fmaxf(b4.y, 0.f);
            b4.z = fmaxf(b4.z, 0.f); b4.w = fmaxf(b4.w, 0.f);
            *(float4*)(x_new + ((size_t)n * BS + r) * DIM + l * 4) = b4;
            if (l == 0) pb_new[n * BS + r] = 0.f;
            return;
        }
    }

    for (int i = threadIdx.x; i < 64 * DIM; i += LBLK) sW[i] = W_lin_l[i];
    if (threadIdx.x < DIM) sB[threadIdx.x] = b_lin_l[threadIdx.x];

    float4 xr4, ag4 = make_float4(0.f, 0.f, 0.f, 0.f);
    float pbm;
    if (L0) {
        xr4 = (n == h0r) ? q4 : make_float4(0.f, 0.f, 0.f, 0.f);
        pbm = (n == h0r) ? 1.f : 0.f;
    } else {
        xr4 = *(const float4*)(x_old + ((size_t)n * BS + r) * DIM + l * 4);
        pbm = pb_old[n * BS + r];
    }

    #pragma unroll 2
    for (int k = s0; k < s1; k++) {
        int2 p2 = es[k];
        int s = p2.x & 0xFFFFF;
        int et = ((unsigned)p2.x) >> 20;
        int e = p2.y;
        if (L0) {
            if (s == h0r) {
                float4 rl = *(const float4*)(rel_l + ((size_t)et * BS + r) * DIM + l * 4);
                float4 ea = *(const float4*)(edge_attr + (size_t)e * DIM + l * 4);
                ag4.x += q4.x * (rl.x + ea.x);
                ag4.y += q4.y * (rl.y + ea.y);
                ag4.z += q4.z * (rl.z + ea.z);
                ag4.w += q4.w * (rl.w + ea.w);
                pbm = 1.f;
            }
        } else {
            float4 xs = *(const float4*)(x_old + ((size_t)s * BS + r) * DIM + l * 4);
            float4 rl = *(const float4*)(rel_l + ((size_t)et * BS + r) * DIM + l * 4);
            float4 ea = *(const float4*)(edge_attr + (size_t)e * DIM + l * 4);
            ag4.x += xs.x * (rl.x + ea.x);
            ag4.y += xs.y * (rl.y + ea.y);
            ag4.z += xs.z * (rl.z + ea.z);
            ag4.w += xs.w * (rl.w + ea.w);
            pbm = fmaxf(pbm, pb_old[s * BS + r]);
        }
    }
    if (n == h0r) {  // agg += boundary
        ag4.x += q4.x; ag4.y += q4.y; ag4.z += q4.z; ag4.w += q4.w;
    }

    float* srow = sIn + (gi * BS + r) * 68;
    *(float4*)(srow + l * 4) = xr4;          // concat [x | agg]
    *(float4*)(srow + 32 + l * 4) = ag4;
    __syncthreads();                          // block-uniform here

    float4 acc = *(const float4*)(sB + l * 4);
    #pragma unroll
    for (int k4 = 0; k4 < 16; k4++) {
        float4 v = *(const float4*)(srow + k4 * 4);
        const float* wb = sW + (k4 * 4) * DIM + l * 4;
        float4 w0 = *(const float4*)(wb);
        float4 w1 = *(const float4*)(wb + DIM);
        float4 w2 = *(const float4*)(wb + 2 * DIM);
        float4 w3 = *(const float4*)(wb + 3 * DIM);
        acc.x += v.x * w0.x + v.y * w1.x + v.z * w2.x + v.w * w3.x;
        acc.y += v.x * w0.y + v.y * w1.y + v.z * w2.y + v.w * w3.y;
        acc.z += v.x * w0.z + v.y * w1.z + v.z * w2.z + v.w * w3.z;
        acc.w += v.x * w0.w + v.y * w1.w + v.z * w2.w + v.w * w3.w;
    }
    acc.x = fmaxf(acc.x, 0.f);
    acc.y = fmaxf(acc.y, 0.f);
    acc.z = fmaxf(acc.z, 0.f);
    acc.w = fmaxf(acc.w, 0.f);
    *(float4*)(x_new + ((size_t)n * BS + r) * DIM + l * 4) = acc;
    if (l == 0) pb_new[n * BS + r] = pbm;
}

// Data-parallel epilogue: 1 block x 1024 threads, LDS-staged.
__launch_bounds__(1024)
__global__ void k_final(const float* __restrict__ x, const float* __restrict__ pb,
                        const int* __restrict__ t_idx,
                        const float* __restrict__ W1, const float* __restrict__ b1,
                        const float* __restrict__ W2, const float* __restrict__ b2,
                        float* __restrict__ out) {
    __shared__ float sW1[DIM * DIM];
    __shared__ float sW2[DIM * DIM];
    __shared__ float sfeat[BATCH * NEG * DIM];
    __shared__ float shid[BATCH * NEG * DIM];
    const int t = threadIdx.x;
    const int NPAIR = BATCH * NEG;  // 128

    for (int i = t; i < DIM * DIM; i += 1024) { sW1[i] = W1[i]; sW2[i] = W2[i]; }

    for (int i = t; i < NPAIR * DIM; i += 1024) {
        int pair = i >> 5;
        int d = i & 31;
        int b = pair >> 5;
        int tt = t_idx[pair];
        float s = 0.f;
        #pragma unroll
        for (int rep = 0; rep < NREP; rep++)
            s += x[((size_t)tt * BS + rep * BATCH + b) * DIM + d];
        sfeat[i] = s * (1.f / 3.f);
    }
    __syncthreads();

    for (int i = t; i < NPAIR * DIM; i += 1024) {
        int pair = i >> 5;
        int jj = i & 31;
        float a = b1[jj];
        #pragma unroll
        for (int k = 0; k < DIM; k++)
            a += sfeat[pair * DIM + k] * sW1[k * DIM + jj];
        shid[i] = fmaxf(a, 0.f);
    }
    __syncthreads();

    for (int i = t; i < NPAIR * DIM; i += 1024) {
        int pair = i >> 5;
        int jj = i & 31;
        float a = b2[jj];
        #pragma unroll
        for (int k = 0; k < DIM; k++)
            a += shid[pair * DIM + k] * sW2[k * DIM + jj];
        out[i] = a;
    }

    if (t < NPAIR) {
        int b = t >> 5;
        int tt = t_idx[t];
        float pm = 0.f;
        #pragma unroll
        for (int rep = 0; rep < NREP; rep++)
            pm = fmaxf(pm, pb[(size_t)tt * BS + rep * BATCH + b]);
        out[NPAIR * DIM + t] = pm;
    }
}

// ---------------------------------------------------------------------
extern "C" void kernel_launch(void* const* d_in, const int* in_sizes, int n_in,
                              void* d_out, int out_size, void* d_ws, size_t ws_size,
                              hipStream_t stream) {
    const int* batch = (const int*)d_in[0];
    const int* edge_index = (const int*)d_in[1];
    const int* edge_type = (const int*)d_in[2];
    const float* edge_attr = (const float*)d_in[3];
    const float* start_query = (const float*)d_in[5];
    const float* W_rel = (const float*)d_in[6];
    const float* b_rel = (const float*)d_in[7];
    const float* W_lin = (const float*)d_in[8];
    const float* b_lin = (const float*)d_in[9];
    const float* W_mlp1 = (const float*)d_in[10];
    const float* b_mlp1 = (const float*)d_in[11];
    const float* W_mlp2 = (const float*)d_in[12];
    const float* b_mlp2 = (const float*)d_in[13];

    float* wf = (float*)d_ws;
    int* wi = (int*)(wf + FLOAT_TOTAL);
    size_t need = FLOAT_TOTAL * sizeof(float) + INT_TOTAL * sizeof(int);
    if (ws_size < need) return;

    float* x_a = wf + XO_A;
    float* x_b = wf + XO_B;
    float* pb_a = wf + PBO_A;
    float* pb_b = wf + PBO_B;
    float* rel = wf + RELO;
    float* q = wf + QO;
    int* h0 = wi + IO_H0;
    int* t_idx = wi + IO_TIDX;
    int* counts = wi + IO_COUNTS;
    int* off = wi + IO_OFF;
    int* bcursor = wi + IO_BCUR;
    int* cursor = wi + IO_CURSOR;
    int* node_order = wi + IO_ORDER;
    int2* es = (int2*)(wi + IO_ES);

    const int* src = edge_index;
    const int* dst = edge_index + N_EDGES;

    hipMemsetAsync(counts, 0, (size_t)N_NODES * sizeof(int), stream);

    k_count<<<EB, 256, 0, stream>>>(dst, counts);
    k_scan<<<1, 1024, 0, stream>>>(counts, off, cursor, bcursor,
                                   batch, start_query, q, h0, t_idx);
    k_prep<<<PREP_GRID, 256, 0, stream>>>(src, dst, edge_type, cursor, es,
                                          counts, bcursor, node_order,
                                          q, W_rel, b_rel, rel);

    // layer 0 (boundary input, fill+fix fast path) -> x_a, pb_a
    k_layer<true><<<GRID_LAYER, LBLK, 0, stream>>>(
        x_a, pb_a, rel, edge_attr, es, off, node_order, h0, q,
        W_lin, b_lin, x_a, pb_a);

    float* x_cur = x_a;
    float* x_nxt = x_b;
    float* pb_cur = pb_a;
    float* pb_nxt = pb_b;
    for (int l = 1; l < NLAYERS; l++) {
        k_layer<false><<<GRID_LAYER, LBLK, 0, stream>>>(
            x_cur, pb_cur, rel + (size_t)l * R2 * BS * DIM, edge_attr, es, off,
            node_order, h0, q,
            W_lin + (size_t)l * 64 * DIM, b_lin + (size_t)l * DIM,
            x_nxt, pb_nxt);
        float* tx = x_cur; x_cur = x_nxt; x_nxt = tx;
        float* tp = pb_cur; pb_cur = pb_nxt; pb_nxt = tp;
    }

    k_final<<<1, 1024, 0, stream>>>(x_cur, pb_cur, t_idx, W_mlp1, b_mlp1, W_mlp2, b_mlp2,
                                    (float*)d_out);
}